// Round 2
// baseline (1269.420 us; speedup 1.0000x reference)
//
#include <hip/hip_runtime.h>
#include <math.h>

#define BATCH 256
#define QL 50
#define EMB 50
#define DL 2000
#define NB 11
#define SEG 8
#define RPS 250      // d rows per segment (DL/SEG), 1 row per thread
#define TPB 256
#define QC 25        // q-chunk size (2 chunks cover QL=50)
#define HB (QL * NB) // 550

// ---------------- macro machinery: named scalar registers ----------------
// Guarantees register residency: no private array can be demoted to scratch.
#define FOR_E50(M) M(0) M(1) M(2) M(3) M(4) M(5) M(6) M(7) M(8) M(9) \
  M(10) M(11) M(12) M(13) M(14) M(15) M(16) M(17) M(18) M(19) \
  M(20) M(21) M(22) M(23) M(24) M(25) M(26) M(27) M(28) M(29) \
  M(30) M(31) M(32) M(33) M(34) M(35) M(36) M(37) M(38) M(39) \
  M(40) M(41) M(42) M(43) M(44) M(45) M(46) M(47) M(48) M(49)

#define FOR_P25(M) M(0,1) M(2,3) M(4,5) M(6,7) M(8,9) M(10,11) M(12,13) \
  M(14,15) M(16,17) M(18,19) M(20,21) M(22,23) M(24,25) M(26,27) M(28,29) \
  M(30,31) M(32,33) M(34,35) M(36,37) M(38,39) M(40,41) M(42,43) M(44,45) \
  M(46,47) M(48,49)

#define FOR_J25(M) M(0) M(1) M(2) M(3) M(4) M(5) M(6) M(7) M(8) M(9) \
  M(10) M(11) M(12) M(13) M(14) M(15) M(16) M(17) M(18) M(19) \
  M(20) M(21) M(22) M(23) M(24)

#define FOR_J25E(M,e) M(e,0) M(e,1) M(e,2) M(e,3) M(e,4) M(e,5) M(e,6) \
  M(e,7) M(e,8) M(e,9) M(e,10) M(e,11) M(e,12) M(e,13) M(e,14) M(e,15) \
  M(e,16) M(e,17) M(e,18) M(e,19) M(e,20) M(e,21) M(e,22) M(e,23) M(e,24)

#define DCLD(e) float d##e;
#define DCLA(j) float a##j = 0.f;

// d-row load: float2 pairs, fmaf norm chain in the exact order of the
// previously-passing kernel (bitwise identical ss).
#define LDP(e0,e1) { const float2 v = *(const float2*)(src + e0); \
  d##e0 = v.x; d##e1 = v.y; \
  ss = fmaf(v.x, v.x, ss); ss = fmaf(v.y, v.y, ss); }

// inner product step: acc_j += d_e * qT[e][cbase+j]; q value is wave-uniform
// -> s_load -> v_fmac_f32 v, s, v (one SGPR operand, legal).
#define FMAJ(e,j) a##j = fmaf(d##e, qcol[j], a##j);
#define DO_E(e) { const float* qcol = qTb + (e) * QL + cbase; FOR_J25E(FMAJ,e) }

// per-q binning + ballot histogram (arithmetic order identical to prior kernel)
#define HIST(j) { const int q = cbase + (j); \
  if (qidb[q] > 0) { \
    const float s_  = a##j * qrnb[q] * drn; \
    const float tt_ = ((s_ + 1.000001f) * 0.5f) * 10.0f; \
    int bb_ = (int)tt_; bb_ = bb_ < 0 ? 0 : (bb_ > 10 ? 10 : bb_); \
    const int bin_ = dval ? bb_ : -1; \
    unsigned cnt_ = 0; \
    _Pragma("unroll") \
    for (int k = 0; k < NB; ++k) { \
      const unsigned long long m_ = __ballot(bin_ == k); \
      if (lane == k) cnt_ = (unsigned)__popcll(m_); \
    } \
    if (lane < NB && cnt_) atomicAdd(&s_hist[q * NB + lane], cnt_); \
  } }

// ---------------- prologue: zero hist, transpose q, q-norms, gate dot ----------------
__global__ __launch_bounds__(TPB)
void prologue_kernel(const float* __restrict__ qe,
                     const float* __restrict__ Wg,
                     float* __restrict__ qT,      // [B][EMB][QL]
                     float* __restrict__ qrn_g,   // [B][QL]
                     float* __restrict__ gate,    // [B]
                     unsigned* __restrict__ g_hist)
{
    const int b = blockIdx.x;
    const int t = threadIdx.x;
    const float* qb = qe + (size_t)b * QL * EMB;

    for (int i = t; i < HB; i += TPB) g_hist[(size_t)b * HB + i] = 0u;

    for (int i = t; i < QL * EMB; i += TPB) {
        const int q = i / EMB;
        const int e = i - q * EMB;
        qT[(size_t)b * QL * EMB + e * QL + q] = qb[i];
    }

    if (t < QL) {
        const float* qr = qb + t * EMB;
        float ss = 0.f;
        #pragma unroll
        for (int e = 0; e < EMB; ++e) ss = fmaf(qr[e], qr[e], ss);
        qrn_g[b * QL + t] = 1.0f / (sqrtf(ss) + 1e-8f);
    }

    // gate dot: exact replica of the old ffn_gate a2 reduction (bitwise identical)
    float a2 = 0.f;
    for (int i = t; i < QL * EMB; i += TPB)
        a2 = fmaf(qb[i], Wg[i], a2);
    #pragma unroll
    for (int off = 32; off > 0; off >>= 1) a2 += __shfl_down(a2, off, 64);
    __shared__ float r2s[4];
    if ((t & 63) == 0) r2s[t >> 6] = a2;
    __syncthreads();
    if (t == 0) gate[b] = r2s[0] + r2s[1] + r2s[2] + r2s[3];
}

// ---------------- main kernel: outer-product sim + histogram ----------------
__global__ __launch_bounds__(TPB, 4)
void sim_hist_kernel(const float* __restrict__ de,
                     const int*   __restrict__ did,
                     const float* __restrict__ qT,
                     const float* __restrict__ qrn_g,
                     const int*   __restrict__ qid,
                     unsigned*    __restrict__ g_hist)
{
    const int bid  = blockIdx.x;
    const int b    = bid >> 3;
    const int seg  = bid & 7;
    const int t    = threadIdx.x;
    const int lane = t & 63;

    __shared__ unsigned s_hist[HB];
    for (int i = t; i < HB; i += TPB) s_hist[i] = 0u;

    // ---- this thread's single d row -> 50 named scalar registers ----
    const bool ok  = t < RPS;
    const int  row = seg * RPS + (ok ? t : 0);
    const float* src = de + ((size_t)b * DL + row) * EMB;

    FOR_E50(DCLD)
    float ss = 0.f;
    FOR_P25(LDP)
    const float drn  = 1.0f / (sqrtf(ss) + 1e-8f);
    const int   dval = (ok && did[(size_t)b * DL + row] > 0) ? 1 : 0;

    __syncthreads();   // s_hist zero-init visible

    const float* qTb  = qT    + (size_t)b * EMB * QL;
    const float* qrnb = qrn_g + (size_t)b * QL;
    const int*   qidb = qid   + (size_t)b * QL;

    for (int c = 0; c < 2; ++c) {
        const int cbase = c * QC;
        FOR_J25(DCLA)          // a0..a24 = 0
        FOR_E50(DO_E)          // 50 e-steps x 25 fmacs, q from SGPRs
        FOR_J25(HIST)          // bin + ballot histogram for this q chunk
    }

    __syncthreads();
    for (int i = t; i < HB; i += TPB) {
        const unsigned cv = s_hist[i];
        if (cv) atomicAdd(&g_hist[(size_t)b * HB + i], cv);
    }
}

// ---------------- ffn dot per batch ----------------
__global__ __launch_bounds__(TPB)
void ffn_kernel(const unsigned* __restrict__ g_hist,
                const float* __restrict__ W1,
                const float* __restrict__ bias,
                float* __restrict__ ffn)
{
    const int b = blockIdx.x;
    const int t = threadIdx.x;

    float a1 = 0.f;
    for (int i = t; i < HB; i += TPB)
        a1 = fmaf(logf((float)g_hist[(size_t)b * HB + i] + 1e-5f), W1[i], a1);

    #pragma unroll
    for (int off = 32; off > 0; off >>= 1) a1 += __shfl_down(a1, off, 64);
    __shared__ float r1s[4];
    if ((t & 63) == 0) r1s[t >> 6] = a1;
    __syncthreads();
    if (t == 0) ffn[b] = r1s[0] + r1s[1] + r1s[2] + r1s[3] + bias[0];
}

// ---------------- softmax over batch + final score ----------------
__global__ __launch_bounds__(TPB)
void score_kernel(const float* __restrict__ ffn,
                  const float* __restrict__ gate,
                  float* __restrict__ out)
{
    const int t = threadIdx.x;  // one block of 256 == BATCH
    __shared__ float buf[4];
    __shared__ float sM, sZ, sS;

    const float g = gate[t];

    float m = g;
    #pragma unroll
    for (int off = 32; off > 0; off >>= 1) m = fmaxf(m, __shfl_down(m, off, 64));
    if ((t & 63) == 0) buf[t >> 6] = m;
    __syncthreads();
    if (t == 0) sM = fmaxf(fmaxf(buf[0], buf[1]), fmaxf(buf[2], buf[3]));
    __syncthreads();

    const float e = expf(g - sM);
    float z = e;
    #pragma unroll
    for (int off = 32; off > 0; off >>= 1) z += __shfl_down(z, off, 64);
    __syncthreads();
    if ((t & 63) == 0) buf[t >> 6] = z;
    __syncthreads();
    if (t == 0) sZ = buf[0] + buf[1] + buf[2] + buf[3];
    __syncthreads();

    float p = e / sZ;
    float s = p;
    #pragma unroll
    for (int off = 32; off > 0; off >>= 1) s += __shfl_down(s, off, 64);
    __syncthreads();
    if ((t & 63) == 0) buf[t >> 6] = s;
    __syncthreads();
    if (t == 0) sS = buf[0] + buf[1] + buf[2] + buf[3];
    __syncthreads();

    out[t] = ffn[t] * sS;
}

// ---------------- launcher ----------------
extern "C" void kernel_launch(void* const* d_in, const int* in_sizes, int n_in,
                              void* d_out, int out_size, void* d_ws, size_t ws_size,
                              hipStream_t stream)
{
    const float* qe  = (const float*)d_in[0];
    const float* de  = (const float*)d_in[1];
    const float* W1  = (const float*)d_in[2];
    const float* b1  = (const float*)d_in[3];
    const float* Wg  = (const float*)d_in[4];
    const int*   qid = (const int*)d_in[5];
    const int*   did = (const int*)d_in[6];
    float* out = (float*)d_out;

    // workspace layout (total ~3.18 MB)
    char* ws = (char*)d_ws;
    float*    qT     = (float*)ws;                               // 2,560,000 B
    unsigned* g_hist = (unsigned*)(ws + 2560000);                //   563,200 B
    float*    qrn    = (float*)(ws + 2560000 + 563200);          //    51,200 B
    float*    ffn    = (float*)(ws + 2560000 + 563200 + 51200);  //     1,024 B
    float*    gate   = ffn + BATCH;                              //     1,024 B

    prologue_kernel<<<BATCH, TPB, 0, stream>>>(qe, Wg, qT, qrn, gate, g_hist);
    sim_hist_kernel<<<BATCH * SEG, TPB, 0, stream>>>(de, did, qT, qrn, qid, g_hist);
    ffn_kernel<<<BATCH, TPB, 0, stream>>>(g_hist, W1, b1, ffn);
    score_kernel<<<1, TPB, 0, stream>>>(ffn, gate, out);
}

// Round 3
// 611.834 us; speedup vs baseline: 2.0748x; 2.0748x over previous
//
#include <hip/hip_runtime.h>
#include <math.h>

#define BATCH 256
#define QL 50
#define EMB 50
#define DL 2000
#define NB 11
#define SEG 8
#define RPS 250      // d rows per segment (DL/SEG), 1 row per thread
#define TPB 256
#define EP 25        // e-pairs (EMB/2)
#define QCH 10       // q per chunk
#define NCH 5        // chunks (QL/QCH)
#define HB (QL * NB) // 550

// ---- small macro helpers over j = 0..9 (10 accumulators max live) ----
#define FOR_J10(M) M(0) M(1) M(2) M(3) M(4) M(5) M(6) M(7) M(8) M(9)

#define DCLA(j) float a##j = 0.f;

// inner FMA: e = 2*ep then 2*ep+1 -> ascending-e fmaf chain per q (bitwise
// identical to the round-0 passing kernel's accumulation order)
#define FMA1(j) { const float2 qv = qpc[ep * QL + (j)]; \
  a##j = fmaf(dv.x, qv.x, a##j); \
  a##j = fmaf(dv.y, qv.y, a##j); }

// binning + ballot histogram — arithmetic replica of the passing kernel
#define HIST1(j) { const int q = qc * QCH + (j); \
  if (s_qv[q]) { \
    const float s_  = a##j * s_qrn[q] * drn; \
    const float tt_ = ((s_ + 1.000001f) * 0.5f) * 10.0f; \
    int bb_ = (int)tt_; bb_ = bb_ < 0 ? 0 : (bb_ > 10 ? 10 : bb_); \
    const int bin_ = dval ? bb_ : -1; \
    unsigned cnt_ = 0; \
    _Pragma("unroll") \
    for (int k = 0; k < NB; ++k) { \
      const unsigned long long m_ = __ballot(bin_ == k); \
      if (lane == k) cnt_ = (unsigned)__popcll(m_); \
    } \
    if (lane < NB && cnt_) atomicAdd(&s_hist[q * NB + lane], cnt_); \
  } }

// ---------------- qprep: zero hist, build q e-pairs, q-norms, gate dot ----------------
__global__ __launch_bounds__(TPB)
void qprep_kernel(const float* __restrict__ qe,
                  const float* __restrict__ Wg,
                  float2* __restrict__ qp,      // [B][EP][QL] float2 pairs
                  float* __restrict__ qrn_g,    // [B][QL]
                  float* __restrict__ gate,     // [B]
                  unsigned* __restrict__ g_hist)
{
    const int b = blockIdx.x;
    const int t = threadIdx.x;
    const float* qb = qe + (size_t)b * QL * EMB;

    for (int i = t; i < HB; i += TPB) g_hist[(size_t)b * HB + i] = 0u;

    // qp[b][ep][q] = { qe[b][q][2ep], qe[b][q][2ep+1] }
    for (int i = t; i < EP * QL; i += TPB) {
        const int ep = i / QL;
        const int q  = i - ep * QL;
        qp[(size_t)b * EP * QL + i] =
            make_float2(qb[q * EMB + 2 * ep], qb[q * EMB + 2 * ep + 1]);
    }

    if (t < QL) {
        const float* qr = qb + t * EMB;
        float ss = 0.f;
        #pragma unroll
        for (int e = 0; e < EMB; ++e) ss = fmaf(qr[e], qr[e], ss);
        qrn_g[b * QL + t] = 1.0f / (sqrtf(ss) + 1e-8f);
    }

    // gate dot: exact replica of the verified reduction (round-2 passed)
    float a2 = 0.f;
    for (int i = t; i < QL * EMB; i += TPB)
        a2 = fmaf(qb[i], Wg[i], a2);
    #pragma unroll
    for (int off = 32; off > 0; off >>= 1) a2 += __shfl_down(a2, off, 64);
    __shared__ float r2s[4];
    if ((t & 63) == 0) r2s[t >> 6] = a2;
    __syncthreads();
    if (t == 0) gate[b] = r2s[0] + r2s[1] + r2s[2] + r2s[3];
}

// ---------------- main kernel: d-rows in LDS, q via scalar loads ----------------
__global__ __launch_bounds__(TPB)
void sim_hist_kernel(const float* __restrict__ de,
                     const int*   __restrict__ did,
                     const float2* __restrict__ qp,
                     const float* __restrict__ qrn_g,
                     const int*   __restrict__ qid,
                     unsigned*    __restrict__ g_hist)
{
    const int bid  = blockIdx.x;
    const int b    = bid >> 3;
    const int seg  = bid & 7;
    const int t    = threadIdx.x;
    const int lane = t & 63;

    __shared__ float2   d2[EP][TPB];   // 51,200 B: e-pair major, lane minor
    __shared__ float    s_qrn[QL];
    __shared__ int      s_qv[QL];
    __shared__ unsigned s_hist[HB];

    for (int i = t; i < HB; i += TPB) s_hist[i] = 0u;
    if (t < QL) {
        s_qrn[t] = qrn_g[b * QL + t];
        s_qv[t]  = (qid[(size_t)b * QL + t] > 0) ? 1 : 0;
    }

    // ---- stage this thread's d row into LDS; norm chain e-ascending ----
    const bool ok  = t < RPS;
    const int  row = seg * RPS + (ok ? t : 0);
    const float* src = de + ((size_t)b * DL + row) * EMB;
    float ss = 0.f;
    #pragma unroll
    for (int ep = 0; ep < EP; ++ep) {
        const float2 v = *(const float2*)(src + 2 * ep);
        ss = fmaf(v.x, v.x, ss);
        ss = fmaf(v.y, v.y, ss);
        d2[ep][t] = v;
    }
    const float drn  = 1.0f / (sqrtf(ss) + 1e-8f);
    const int   dval = (ok && did[(size_t)b * DL + row] > 0) ? 1 : 0;

    __syncthreads();

    const float2* qpb = qp + (size_t)b * EP * QL;

    for (int qc = 0; qc < NCH; ++qc) {
        FOR_J10(DCLA)                       // a0..a9 = 0  (~25 live VGPRs total)
        const float2* qpc = qpb + qc * QCH; // wave-uniform -> s_load
        #pragma unroll
        for (int ep = 0; ep < EP; ++ep) {
            const float2 dv = d2[ep][t];    // ds_read_b64, 2-way bank (free)
            FOR_J10(FMA1)                   // 20 v_fmac, q from SGPRs
        }
        FOR_J10(HIST1)                      // bin + ballot for this q chunk
    }

    __syncthreads();
    for (int i = t; i < HB; i += TPB) {
        const unsigned cv = s_hist[i];
        if (cv) atomicAdd(&g_hist[(size_t)b * HB + i], cv);
    }
}

// ---------------- ffn dot per batch (verbatim from passing round-2) ----------------
__global__ __launch_bounds__(TPB)
void ffn_kernel(const unsigned* __restrict__ g_hist,
                const float* __restrict__ W1,
                const float* __restrict__ bias,
                float* __restrict__ ffn)
{
    const int b = blockIdx.x;
    const int t = threadIdx.x;

    float a1 = 0.f;
    for (int i = t; i < HB; i += TPB)
        a1 = fmaf(logf((float)g_hist[(size_t)b * HB + i] + 1e-5f), W1[i], a1);

    #pragma unroll
    for (int off = 32; off > 0; off >>= 1) a1 += __shfl_down(a1, off, 64);
    __shared__ float r1s[4];
    if ((t & 63) == 0) r1s[t >> 6] = a1;
    __syncthreads();
    if (t == 0) ffn[b] = r1s[0] + r1s[1] + r1s[2] + r1s[3] + bias[0];
}

// ---------------- softmax over batch + final score (verbatim) ----------------
__global__ __launch_bounds__(TPB)
void score_kernel(const float* __restrict__ ffn,
                  const float* __restrict__ gate,
                  float* __restrict__ out)
{
    const int t = threadIdx.x;  // one block of 256 == BATCH
    __shared__ float buf[4];
    __shared__ float sM, sZ, sS;

    const float g = gate[t];

    float m = g;
    #pragma unroll
    for (int off = 32; off > 0; off >>= 1) m = fmaxf(m, __shfl_down(m, off, 64));
    if ((t & 63) == 0) buf[t >> 6] = m;
    __syncthreads();
    if (t == 0) sM = fmaxf(fmaxf(buf[0], buf[1]), fmaxf(buf[2], buf[3]));
    __syncthreads();

    const float e = expf(g - sM);
    float z = e;
    #pragma unroll
    for (int off = 32; off > 0; off >>= 1) z += __shfl_down(z, off, 64);
    __syncthreads();
    if ((t & 63) == 0) buf[t >> 6] = z;
    __syncthreads();
    if (t == 0) sZ = buf[0] + buf[1] + buf[2] + buf[3];
    __syncthreads();

    float p = e / sZ;
    float s = p;
    #pragma unroll
    for (int off = 32; off > 0; off >>= 1) s += __shfl_down(s, off, 64);
    __syncthreads();
    if ((t & 63) == 0) buf[t >> 6] = s;
    __syncthreads();
    if (t == 0) sS = buf[0] + buf[1] + buf[2] + buf[3];
    __syncthreads();

    out[t] = ffn[t] * sS;
}

// ---------------- launcher ----------------
extern "C" void kernel_launch(void* const* d_in, const int* in_sizes, int n_in,
                              void* d_out, int out_size, void* d_ws, size_t ws_size,
                              hipStream_t stream)
{
    const float* qe  = (const float*)d_in[0];
    const float* de  = (const float*)d_in[1];
    const float* W1  = (const float*)d_in[2];
    const float* b1  = (const float*)d_in[3];
    const float* Wg  = (const float*)d_in[4];
    const int*   qid = (const int*)d_in[5];
    const int*   did = (const int*)d_in[6];
    float* out = (float*)d_out;

    // workspace layout — same total as the round-2 run that passed (~3.18 MB)
    char* ws = (char*)d_ws;
    float2*   qp     = (float2*)ws;                              // 2,560,000 B
    unsigned* g_hist = (unsigned*)(ws + 2560000);                //   563,200 B
    float*    qrn    = (float*)(ws + 2560000 + 563200);          //    51,200 B
    float*    ffn    = (float*)(ws + 2560000 + 563200 + 51200);  //     1,024 B
    float*    gate   = ffn + BATCH;                              //     1,024 B

    qprep_kernel<<<BATCH, TPB, 0, stream>>>(qe, Wg, qp, qrn, gate, g_hist);
    sim_hist_kernel<<<BATCH * SEG, TPB, 0, stream>>>(de, did, qp, qrn, qid, g_hist);
    ffn_kernel<<<BATCH, TPB, 0, stream>>>(g_hist, W1, b1, ffn);
    score_kernel<<<1, TPB, 0, stream>>>(ffn, gate, out);
}

// Round 4
// 310.043 us; speedup vs baseline: 4.0943x; 1.9734x over previous
//
#include <hip/hip_runtime.h>
#include <math.h>

#define BATCH 256
#define QL 50
#define EMB 50
#define DL 2000
#define NB 11
#define SEG 8
#define RPS 250      // d rows per segment (DL/SEG), 1 row per thread
#define TPB 256
#define EP 25        // e-pairs per d row
#define QCH 10       // q per chunk
#define NCH 5        // q chunks
#define NEC 5        // e chunks (5 float2 each)
#define HB (QL * NB) // 550

#define FOR_J10(M) M(0) M(1) M(2) M(3) M(4) M(5) M(6) M(7) M(8) M(9)
#define DCLA(j) float a##j = 0.f;

// inner: 5 broadcast q float2 reads, 10 fmacs; e ascending (bitwise-exact chain)
#define FMAQ(j) { \
  const float2* qrow = (const float2*)&s_q[qc * QCH + (j)][ec * 10]; \
  float2 qv; \
  qv = qrow[0]; a##j = fmaf(dv0.x, qv.x, a##j); a##j = fmaf(dv0.y, qv.y, a##j); \
  qv = qrow[1]; a##j = fmaf(dv1.x, qv.x, a##j); a##j = fmaf(dv1.y, qv.y, a##j); \
  qv = qrow[2]; a##j = fmaf(dv2.x, qv.x, a##j); a##j = fmaf(dv2.y, qv.y, a##j); \
  qv = qrow[3]; a##j = fmaf(dv3.x, qv.x, a##j); a##j = fmaf(dv3.y, qv.y, a##j); \
  qv = qrow[4]; a##j = fmaf(dv4.x, qv.x, a##j); a##j = fmaf(dv4.y, qv.y, a##j); }

// binning + ballot histogram — verbatim arithmetic from the passing kernels
#define HIST1(j) { const int q = qc * QCH + (j); \
  if (s_qv[q]) { \
    const float s_  = a##j * s_qrn[q] * drn; \
    const float tt_ = ((s_ + 1.000001f) * 0.5f) * 10.0f; \
    int bb_ = (int)tt_; bb_ = bb_ < 0 ? 0 : (bb_ > 10 ? 10 : bb_); \
    const int bin_ = dval ? bb_ : -1; \
    unsigned cnt_ = 0; \
    _Pragma("unroll") \
    for (int k = 0; k < NB; ++k) { \
      const unsigned long long m_ = __ballot(bin_ == k); \
      if (lane == k) cnt_ = (unsigned)__popcll(m_); \
    } \
    if (lane < NB && cnt_) atomicAdd(&s_hist[q * NB + lane], cnt_); \
  } }

// ---------------- gate kernel: zero hist + gate dot (verbatim, passed) ----------------
__global__ __launch_bounds__(TPB)
void gate_kernel(const float* __restrict__ qe,
                 const float* __restrict__ Wg,
                 float* __restrict__ gate,
                 unsigned* __restrict__ g_hist)
{
    const int b = blockIdx.x;
    const int t = threadIdx.x;
    const float* qb = qe + (size_t)b * QL * EMB;

    for (int i = t; i < HB; i += TPB) g_hist[(size_t)b * HB + i] = 0u;

    float a2 = 0.f;
    for (int i = t; i < QL * EMB; i += TPB)
        a2 = fmaf(qb[i], Wg[i], a2);
    #pragma unroll
    for (int off = 32; off > 0; off >>= 1) a2 += __shfl_down(a2, off, 64);
    __shared__ float r2s[4];
    if ((t & 63) == 0) r2s[t >> 6] = a2;
    __syncthreads();
    if (t == 0) gate[b] = r2s[0] + r2s[1] + r2s[2] + r2s[3];
}

// ---------------- main kernel: d in LDS (lane-major), q in LDS (broadcast) ----------------
__global__ __launch_bounds__(TPB)
void sim_hist_kernel(const float* __restrict__ de,
                     const int*   __restrict__ did,
                     const float* __restrict__ qe,
                     const int*   __restrict__ qid,
                     unsigned*    __restrict__ g_hist)
{
    const int bid  = blockIdx.x;
    const int b    = bid >> 3;
    const int seg  = bid & 7;
    const int t    = threadIdx.x;
    const int lane = t & 63;

    __shared__ float2   d2[EP][TPB];    // 51,200 B  (lane-minor: 2-way bank, free)
    __shared__ float    s_q[QL][EMB];   // 10,000 B  (broadcast reads)
    __shared__ float    s_qrn[QL];
    __shared__ int      s_qv[QL];
    __shared__ unsigned s_hist[HB];     // total ~63.8 KB -> 2 blocks/CU

    for (int i = t; i < HB; i += TPB) s_hist[i] = 0u;

    const float* qbase = qe + (size_t)b * QL * EMB;
    for (int i = t; i < QL * EMB; i += TPB) ((float*)s_q)[i] = qbase[i];

    if (t < QL) {   // q-norms + validity (round-0 verbatim)
        const float* qr = qbase + t * EMB;
        float ss = 0.f;
        #pragma unroll
        for (int e = 0; e < EMB; ++e) ss = fmaf(qr[e], qr[e], ss);
        s_qrn[t] = 1.0f / (sqrtf(ss) + 1e-8f);
        s_qv[t]  = (qid[(size_t)b * QL + t] > 0) ? 1 : 0;
    }

    // ---- stage this thread's d row into LDS; norm chain e-ascending (R3 verbatim) ----
    const bool ok  = t < RPS;
    const int  row = seg * RPS + (ok ? t : 0);
    const float* src = de + ((size_t)b * DL + row) * EMB;
    float ss = 0.f;
    #pragma unroll
    for (int ep = 0; ep < EP; ++ep) {
        const float2 v = *(const float2*)(src + 2 * ep);
        ss = fmaf(v.x, v.x, ss);
        ss = fmaf(v.y, v.y, ss);
        d2[ep][t] = v;
    }
    const float drn  = 1.0f / (sqrtf(ss) + 1e-8f);
    const int   dval = (ok && did[(size_t)b * DL + row] > 0) ? 1 : 0;

    __syncthreads();

    #pragma unroll 1
    for (int qc = 0; qc < NCH; ++qc) {
        FOR_J10(DCLA)                       // a0..a9 = 0
        #pragma unroll 1
        for (int ec = 0; ec < NEC; ++ec) {  // ROLLED: bounds live set, kills hoisting
            const float2 dv0 = d2[ec * 5 + 0][t];
            const float2 dv1 = d2[ec * 5 + 1][t];
            const float2 dv2 = d2[ec * 5 + 2][t];
            const float2 dv3 = d2[ec * 5 + 3][t];
            const float2 dv4 = d2[ec * 5 + 4][t];
            FOR_J10(FMAQ)                   // 100 fmacs, 50 broadcast q reads
        }
        FOR_J10(HIST1)                      // bin + ballot for this q chunk
    }

    __syncthreads();
    for (int i = t; i < HB; i += TPB) {
        const unsigned cv = s_hist[i];
        if (cv) atomicAdd(&g_hist[(size_t)b * HB + i], cv);
    }
}

// ---------------- ffn dot per batch (verbatim, passed) ----------------
__global__ __launch_bounds__(TPB)
void ffn_kernel(const unsigned* __restrict__ g_hist,
                const float* __restrict__ W1,
                const float* __restrict__ bias,
                float* __restrict__ ffn)
{
    const int b = blockIdx.x;
    const int t = threadIdx.x;

    float a1 = 0.f;
    for (int i = t; i < HB; i += TPB)
        a1 = fmaf(logf((float)g_hist[(size_t)b * HB + i] + 1e-5f), W1[i], a1);

    #pragma unroll
    for (int off = 32; off > 0; off >>= 1) a1 += __shfl_down(a1, off, 64);
    __shared__ float r1s[4];
    if ((t & 63) == 0) r1s[t >> 6] = a1;
    __syncthreads();
    if (t == 0) ffn[b] = r1s[0] + r1s[1] + r1s[2] + r1s[3] + bias[0];
}

// ---------------- softmax over batch + final score (verbatim, passed) ----------------
__global__ __launch_bounds__(TPB)
void score_kernel(const float* __restrict__ ffn,
                  const float* __restrict__ gate,
                  float* __restrict__ out)
{
    const int t = threadIdx.x;  // one block of 256 == BATCH
    __shared__ float buf[4];
    __shared__ float sM, sZ, sS;

    const float g = gate[t];

    float m = g;
    #pragma unroll
    for (int off = 32; off > 0; off >>= 1) m = fmaxf(m, __shfl_down(m, off, 64));
    if ((t & 63) == 0) buf[t >> 6] = m;
    __syncthreads();
    if (t == 0) sM = fmaxf(fmaxf(buf[0], buf[1]), fmaxf(buf[2], buf[3]));
    __syncthreads();

    const float e = expf(g - sM);
    float z = e;
    #pragma unroll
    for (int off = 32; off > 0; off >>= 1) z += __shfl_down(z, off, 64);
    __syncthreads();
    if ((t & 63) == 0) buf[t >> 6] = z;
    __syncthreads();
    if (t == 0) sZ = buf[0] + buf[1] + buf[2] + buf[3];
    __syncthreads();

    float p = e / sZ;
    float s = p;
    #pragma unroll
    for (int off = 32; off > 0; off >>= 1) s += __shfl_down(s, off, 64);
    __syncthreads();
    if ((t & 63) == 0) buf[t >> 6] = s;
    __syncthreads();
    if (t == 0) sS = buf[0] + buf[1] + buf[2] + buf[3];
    __syncthreads();

    out[t] = ffn[t] * sS;
}

// ---------------- launcher ----------------
extern "C" void kernel_launch(void* const* d_in, const int* in_sizes, int n_in,
                              void* d_out, int out_size, void* d_ws, size_t ws_size,
                              hipStream_t stream)
{
    const float* qe  = (const float*)d_in[0];
    const float* de  = (const float*)d_in[1];
    const float* W1  = (const float*)d_in[2];
    const float* b1  = (const float*)d_in[3];
    const float* Wg  = (const float*)d_in[4];
    const int*   qid = (const int*)d_in[5];
    const int*   did = (const int*)d_in[6];
    float* out = (float*)d_out;

    char* ws = (char*)d_ws;
    unsigned* g_hist = (unsigned*)ws;                 // 563,200 B
    float*    ffn    = (float*)(ws + 563200);         //   1,024 B
    float*    gate   = ffn + BATCH;                   //   1,024 B

    gate_kernel<<<BATCH, TPB, 0, stream>>>(qe, Wg, gate, g_hist);
    sim_hist_kernel<<<BATCH * SEG, TPB, 0, stream>>>(de, did, qe, qid, g_hist);
    ffn_kernel<<<BATCH, TPB, 0, stream>>>(g_hist, W1, b1, ffn);
    score_kernel<<<1, TPB, 0, stream>>>(ffn, gate, out);
}